// Round 2
// 67.499 us; speedup vs baseline: 1.0280x; 1.0280x over previous
//
#include <hip/hip_runtime.h>

// JointBilateral PAC upsample, S=4, K=5, PAD=1, OP=1.
// x (4,1,128,128), guide (4,3,512,512), weight (1,1,5,5) -> out (4,1,512,512).
//
// Tile formulation: one thread per low-res cell (q,m) computes the full 4x4
// output tile rows h=4q+rh, cols w=4m+p.
//   - primary site (4q+1, 4m+1) == center pixel c[ch][1][1] -> NO extra load
//   - secondary sites s01/s10/s11 loaded with clamped offsets, gated by flags
//   - kern = exp(-0.125*||g_site-g_center||^2 - 0.005*(di^2+dj^2)) * w[(4-i)*5+(4-j)]
//   - out = sum(kern*x)/sum(kern)
// Weight (25 floats) loaded once per thread as 6x float4 + 1 scalar.

#define HW_ (512 * 512)

__global__ __launch_bounds__(256) void jbu_tile_kernel(
    const float* __restrict__ x,       // (4,1,128,128)
    const float* __restrict__ guide,   // (4,3,512,512)
    const float* __restrict__ weight,  // (25,)
    float* __restrict__ out)           // (4,1,512,512)
{
    int tid = blockIdx.x * blockDim.x + threadIdx.x;  // 4*128*128 = 65536 threads
    int m = tid & 127;            // low-res col
    int q = (tid >> 7) & 127;     // low-res row (wave-uniform)
    int b = tid >> 14;            // batch (wave-uniform)

    const float* gb = guide + (size_t)b * 3 * HW_;
    const float* xb = x + b * 128 * 128;

    // ---- center guidance: 4 rows x 4 cols x 3 ch, coalesced float4 loads ----
    float c[3][4][4];
    #pragma unroll
    for (int ch = 0; ch < 3; ++ch)
        #pragma unroll
        for (int r = 0; r < 4; ++r) {
            float4 v = *(const float4*)(gb + ch * HW_ + (4 * q + r) * 512 + 4 * m);
            c[ch][r][0] = v.x; c[ch][r][1] = v.y; c[ch][r][2] = v.z; c[ch][r][3] = v.w;
        }

    // ---- secondary-tap existence flags + clamped offsets ----
    bool cs = (m < 127), rs = (q < 127);
    float csf = cs ? 1.0f : 0.0f, rsf = rs ? 1.0f : 0.0f;
    int co = cs ? 4 : 0;          // +4 cols in guide
    int ro = rs ? 4 * 512 : 0;    // +4 rows in guide
    int xo = cs ? 1 : 0;          // +1 col in x
    int xr = rs ? 128 : 0;        // +1 row in x

    // ---- sample sites (3 channels each). s00 is free (center row 1, comp .y) ----
    int sr = (4 * q + 1) * 512 + 4 * m + 1;
    float s00[3], s01[3], s10[3], s11[3];
    #pragma unroll
    for (int ch = 0; ch < 3; ++ch) {
        s00[ch] = c[ch][1][1];
        s01[ch] = gb[ch * HW_ + sr + co];
        s10[ch] = gb[ch * HW_ + sr + ro];
        s11[ch] = gb[ch * HW_ + sr + ro + co];
    }
    float x00 = xb[q * 128 + m];
    float x01 = xb[q * 128 + m + xo];
    float x10 = xb[q * 128 + m + xr];
    float x11 = xb[q * 128 + m + xr + xo];

    // ---- full 5x5 weight, vectorized (weight base is 16B-aligned) ----
    float w_[25];
    #pragma unroll
    for (int k = 0; k < 6; ++k) {
        float4 v = *(const float4*)(weight + 4 * k);
        w_[4 * k] = v.x; w_[4 * k + 1] = v.y; w_[4 * k + 2] = v.z; w_[4 * k + 3] = v.w;
    }
    w_[24] = weight[24];

    // spatial term 0.005*di^2 per sub-pixel position (primary taps); secondary = 0.02
    const float sp[4] = {0.005f, 0.0f, 0.005f, 0.02f};

    size_t obase = (size_t)b * HW_ + (size_t)(4 * q) * 512 + 4 * m;

    #pragma unroll
    for (int r = 0; r < 4; ++r) {
        float acc[4] = {0, 0, 0, 0}, nrm[4] = {0, 0, 0, 0};

        // primary row tap (always valid), primary col for all 4 sub-pixels
        #pragma unroll
        for (int p = 0; p < 4; ++p) {
            float d0 = s00[0] - c[0][r][p];
            float d1 = s00[1] - c[1][r][p];
            float d2 = s00[2] - c[2][r][p];
            float t = d0 * d0 + d1 * d1 + d2 * d2;
            float kv = __expf(-0.125f * t - sp[r] - sp[p]) * w_[(r + 1) * 5 + p + 1];
            nrm[p] += kv; acc[p] += kv * x00;
        }
        {   // col-secondary tap (sub-pixel p==3 only)
            float d0 = s01[0] - c[0][r][3];
            float d1 = s01[1] - c[1][r][3];
            float d2 = s01[2] - c[2][r][3];
            float t = d0 * d0 + d1 * d1 + d2 * d2;
            float kv = __expf(-0.125f * t - sp[r] - 0.02f) * w_[(r + 1) * 5] * csf;
            nrm[3] += kv; acc[3] += kv * x01;
        }
        if (r == 3) {   // row-secondary taps (compile-time branch; rsf gates validity)
            #pragma unroll
            for (int p = 0; p < 4; ++p) {
                float d0 = s10[0] - c[0][3][p];
                float d1 = s10[1] - c[1][3][p];
                float d2 = s10[2] - c[2][3][p];
                float t = d0 * d0 + d1 * d1 + d2 * d2;
                float kv = __expf(-0.125f * t - 0.02f - sp[p]) * w_[p + 1] * rsf;
                nrm[p] += kv; acc[p] += kv * x10;
            }
            float d0 = s11[0] - c[0][3][3];
            float d1 = s11[1] - c[1][3][3];
            float d2 = s11[2] - c[2][3][3];
            float t = d0 * d0 + d1 * d1 + d2 * d2;
            float kv = __expf(-0.125f * t - 0.04f) * w_[0] * (rsf * csf);
            nrm[3] += kv; acc[3] += kv * x11;
        }

        float4 o;
        o.x = acc[0] / nrm[0];
        o.y = acc[1] / nrm[1];
        o.z = acc[2] / nrm[2];
        o.w = acc[3] / nrm[3];
        *(float4*)(out + obase + (size_t)r * 512) = o;
    }
}

extern "C" void kernel_launch(void* const* d_in, const int* in_sizes, int n_in,
                              void* d_out, int out_size, void* d_ws, size_t ws_size,
                              hipStream_t stream) {
    const float* x      = (const float*)d_in[0];
    const float* guide  = (const float*)d_in[1];
    const float* weight = (const float*)d_in[2];
    float* out = (float*)d_out;

    (void)in_sizes; (void)n_in; (void)out_size; (void)d_ws; (void)ws_size;
    int total = 4 * 128 * 128;   // one thread per 4x4 output tile
    jbu_tile_kernel<<<total / 256, 256, 0, stream>>>(x, guide, weight, out);
}